// Round 1
// baseline (2928.474 us; speedup 1.0000x reference)
//
#include <hip/hip_runtime.h>
#include <hip/hip_bf16.h>
#include <math.h>

#define Bn 128
#define Sn 512
#define Tn 256

// ---------------- E = exp(trans) in bf16 ----------------
__global__ void compute_E_kernel(const float* __restrict__ trans, __hip_bfloat16* __restrict__ E) {
    int k = blockIdx.x * blockDim.x + threadIdx.x;
    if (k < Tn * Tn) E[k] = __float2bfloat16(__expf(trans[k]));
}

// ---------------- lengths from mask (dtype auto-detect) ----------------
__global__ void lengths_kernel(const void* __restrict__ mask, int* __restrict__ lengths) {
    int b = blockIdx.x, tid = threadIdx.x;   // 256 threads
    const unsigned int* mu = (const unsigned int*)mask;
    unsigned int w0 = mu[0];
    int cnt = 0;
    if (w0 == 1u) {                       // int32 0/1 layout
        const int* mi = (const int*)mask;
        for (int t = tid; t < Sn; t += 256) cnt += (mi[b * Sn + t] != 0);
    } else if (w0 == 0x3F800000u) {       // float32 0/1 layout
        const float* mf = (const float*)mask;
        for (int t = tid; t < Sn; t += 256) cnt += (mf[b * Sn + t] != 0.0f);
    } else {                              // 1-byte bool layout
        const unsigned char* mb = (const unsigned char*)mask;
        for (int t = tid; t < Sn; t += 256) cnt += (mb[b * Sn + t] != 0);
    }
    for (int off = 32; off; off >>= 1) cnt += __shfl_xor(cnt, off);
    __shared__ int red[4];
    if ((tid & 63) == 0) red[tid >> 6] = cnt;
    __syncthreads();
    if (tid == 0) lengths[b] = red[0] + red[1] + red[2] + red[3];
}

// ---------------- numerator (gold path score) ----------------
__global__ void numerator_kernel(const float* __restrict__ logits, const int* __restrict__ labels,
                                 const float* __restrict__ start_t, const float* __restrict__ end_t,
                                 const float* __restrict__ trans, const int* __restrict__ lengths,
                                 float* __restrict__ num) {
    int b = blockIdx.x, tid = threadIdx.x;   // 256 threads
    int len = lengths[b];
    float acc = 0.0f;
    for (int t = tid + 1; t < len; t += 256) {
        int prev = labels[b * Sn + t - 1], cur = labels[b * Sn + t];
        acc += trans[prev * Tn + cur] + logits[((size_t)b * Sn + t) * Tn + cur];
    }
    for (int off = 32; off; off >>= 1) acc += __shfl_xor(acc, off);
    __shared__ float red[4];
    if ((tid & 63) == 0) red[tid >> 6] = acc;
    __syncthreads();
    if (tid == 0) {
        int l0 = labels[b * Sn];
        int ll = labels[b * Sn + len - 1];
        num[b] = start_t[l0] + logits[(size_t)b * Sn * Tn + l0]
               + red[0] + red[1] + red[2] + red[3] + end_t[ll];
    }
}

// ---------------- fused forward: denominator (logsumexp) + Viterbi ----------------
__launch_bounds__(1024)
__global__ void fused_fwd_kernel(const float* __restrict__ logits,
                                 const float* __restrict__ start_t,
                                 const float* __restrict__ end_t,
                                 const float* __restrict__ trans,
                                 const __hip_bfloat16* __restrict__ E,
                                 const int* __restrict__ lengths,
                                 unsigned char* __restrict__ hist,
                                 float* __restrict__ den_out,
                                 int* __restrict__ last_out) {
    int b = blockIdx.x;
    int tid = threadIdx.x;          // 0..1023
    int j = tid & 255;              // next-tag column this thread owns
    int h = tid >> 8;               // i-quarter 0..3
    int i0 = h * 64;

    __shared__ __align__(16) float sden[Tn];
    __shared__ __align__(16) float svit[Tn];
    __shared__ __align__(16) float p[Tn];
    __shared__ float redf[16];
    __shared__ float reds[16];
    __shared__ float redb[16];
    __shared__ int   redbi[16];
    __shared__ float pd[1024];
    __shared__ float pv[1024];
    __shared__ int   pa[1024];

    int len = lengths[b];
    if (tid < Tn) {
        float v = start_t[j] + logits[(size_t)b * Sn * Tn + j];
        sden[j] = v;
        svit[j] = v;
    }
    __syncthreads();

    for (int t = 1; t < len; ++t) {
        // ---- m = max_i sden[i] ----
        float v = sden[j];
        for (int off = 32; off; off >>= 1) v = fmaxf(v, __shfl_xor(v, off));
        if ((tid & 63) == 0) redf[tid >> 6] = v;
        __syncthreads();
        float m = redf[0];
        #pragma unroll
        for (int w = 1; w < 16; ++w) m = fmaxf(m, redf[w]);
        // ---- p_i = exp(sden_i - m) ----
        if (tid < Tn) p[j] = __expf(sden[j] - m);
        __syncthreads();

        // ---- inner reduction over this thread's i-quarter ----
        float s = 0.0f, best = -INFINITY;
        int arg = 0;
        const float* tr = trans + (size_t)i0 * Tn + j;
        const __hip_bfloat16* er = E + (size_t)i0 * Tn + j;
        #pragma unroll 4
        for (int i = i0; i < i0 + 64; i += 4) {
            float4 p4  = *(const float4*)(p + i);
            float4 sv4 = *(const float4*)(svit + i);
            float tr0 = tr[0 * Tn], tr1 = tr[1 * Tn], tr2 = tr[2 * Tn], tr3 = tr[3 * Tn];
            float e0 = __bfloat162float(er[0 * Tn]);
            float e1 = __bfloat162float(er[1 * Tn]);
            float e2 = __bfloat162float(er[2 * Tn]);
            float e3 = __bfloat162float(er[3 * Tn]);
            tr += 4 * Tn; er += 4 * Tn;
            s = fmaf(p4.x, e0, s); s = fmaf(p4.y, e1, s);
            s = fmaf(p4.z, e2, s); s = fmaf(p4.w, e3, s);
            float c0 = sv4.x + tr0; if (c0 > best) { best = c0; arg = i + 0; }
            float c1 = sv4.y + tr1; if (c1 > best) { best = c1; arg = i + 1; }
            float c2 = sv4.z + tr2; if (c2 > best) { best = c2; arg = i + 2; }
            float c3 = sv4.w + tr3; if (c3 > best) { best = c3; arg = i + 3; }
        }
        pd[tid] = s; pv[tid] = best; pa[tid] = arg;
        __syncthreads();

        // ---- combine quarters (ascending i preserves first-occurrence argmax) ----
        if (tid < Tn) {
            float ss = pd[j] + pd[j + 256] + pd[j + 512] + pd[j + 768];
            float bb = pv[j]; int aa = pa[j];
            if (pv[j + 256] > bb) { bb = pv[j + 256]; aa = pa[j + 256]; }
            if (pv[j + 512] > bb) { bb = pv[j + 512]; aa = pa[j + 512]; }
            if (pv[j + 768] > bb) { bb = pv[j + 768]; aa = pa[j + 768]; }
            float emit = logits[((size_t)b * Sn + t) * Tn + j];
            sden[j] = m + __logf(ss) + emit;
            svit[j] = bb + emit;
            hist[((size_t)t * Bn + b) * Tn + j] = (unsigned char)aa;
        }
        __syncthreads();
    }

    // ---- epilogue: den = logsumexp(sden + end_t), last = argmax(svit + end_t) ----
    float v2d = sden[j] + end_t[j];
    float M = v2d;
    for (int off = 32; off; off >>= 1) M = fmaxf(M, __shfl_xor(M, off));
    if ((tid & 63) == 0) redf[tid >> 6] = M;
    __syncthreads();
    M = redf[0];
    #pragma unroll
    for (int w = 1; w < 16; ++w) M = fmaxf(M, redf[w]);

    float ex = (tid < Tn) ? __expf(v2d - M) : 0.0f;
    for (int off = 32; off; off >>= 1) ex += __shfl_xor(ex, off);

    float v2v = svit[j] + end_t[j];
    float bv = v2v; int bj = j;
    for (int off = 32; off; off >>= 1) {
        float ov = __shfl_xor(bv, off); int oj = __shfl_xor(bj, off);
        if (ov > bv || (ov == bv && oj < bj)) { bv = ov; bj = oj; }
    }
    if ((tid & 63) == 0) { reds[tid >> 6] = ex; redb[tid >> 6] = bv; redbi[tid >> 6] = bj; }
    __syncthreads();
    if (tid == 0) {
        float sum = 0.0f;
        #pragma unroll
        for (int w = 0; w < 16; ++w) sum += reds[w];
        den_out[b] = M + __logf(sum);
        float BB = redb[0]; int AA = redbi[0];
        #pragma unroll
        for (int w = 1; w < 16; ++w)
            if (redb[w] > BB || (redb[w] == BB && redbi[w] < AA)) { BB = redb[w]; AA = redbi[w]; }
        last_out[b] = AA;
    }
}

// ---------------- backtrack (one wave per batch, pipelined row loads) ----------------
__global__ void backtrack_kernel(const unsigned char* __restrict__ hist,
                                 const int* __restrict__ last,
                                 const int* __restrict__ lengths,
                                 float* __restrict__ pred) {
    int b = blockIdx.x, lane = threadIdx.x;   // 64 threads = 1 wave
    int len = lengths[b];
    int len1 = len - 1;                        // number of chain steps
    __shared__ int tg[Sn];
    int tag = last[b];

    const int P = 16;
    unsigned int buf[P];
    #pragma unroll
    for (int q = 0; q < P; ++q) {
        int r = len1 - q;                      // rows len-1 .. len-16
        if (q < len1)
            buf[q] = *(const unsigned int*)(hist + ((size_t)r * Bn + b) * Tn + lane * 4);
    }
    if (lane == 0) tg[len1] = tag;
    for (int q = 0; q < len1; ++q) {
        unsigned int w = buf[q & (P - 1)];
        // select byte `tag` of row: lane tag>>2 holds it, byte tag&3
        int sel = __shfl((int)w, tag >> 2, 64);
        tag = (sel >> ((tag & 3) * 8)) & 255;
        int t = len1 - 1 - q;
        if (lane == 0) tg[t] = tag;
        int rn = len1 - q - P;
        if (rn >= 1)
            buf[q & (P - 1)] = *(const unsigned int*)(hist + ((size_t)rn * Bn + b) * Tn + lane * 4);
    }
    __syncthreads();
    for (int t = lane; t < Sn; t += 64)
        pred[(size_t)b * Sn + t] = (t < len) ? (float)tg[t] : 0.0f;
}

// ---------------- loss = mean(den - num) ----------------
__global__ void loss_kernel(const float* __restrict__ num, const float* __restrict__ den,
                            float* __restrict__ out_loss) {
    int tid = threadIdx.x;   // 128 threads
    float v = den[tid] - num[tid];
    for (int off = 32; off; off >>= 1) v += __shfl_xor(v, off);
    __shared__ float r2[2];
    if ((tid & 63) == 0) r2[tid >> 6] = v;
    __syncthreads();
    if (tid == 0) out_loss[0] = (r2[0] + r2[1]) * (1.0f / 128.0f);
}

extern "C" void kernel_launch(void* const* d_in, const int* in_sizes, int n_in,
                              void* d_out, int out_size, void* d_ws, size_t ws_size,
                              hipStream_t stream) {
    const float* logits  = (const float*)d_in[0];
    const void*  mask    = d_in[1];
    const int*   labels  = (const int*)d_in[2];
    const float* start_t = (const float*)d_in[3];
    const float* end_t   = (const float*)d_in[4];
    const float* trans   = (const float*)d_in[5];
    float* out = (float*)d_out;   // [B*S] pred as float, then [1] loss

    char* ws = (char*)d_ws;
    const size_t histSz = (size_t)Sn * Bn * Tn;        // 16 MB of uint8 history
    unsigned char*  hist    = (unsigned char*)ws;
    int*            lengths = (int*)(ws + histSz);
    float*          num     = (float*)(ws + histSz + 512);
    float*          den     = (float*)(ws + histSz + 1024);
    int*            last    = (int*)(ws + histSz + 1536);
    __hip_bfloat16* E       = (__hip_bfloat16*)(ws + histSz + 2048);

    compute_E_kernel<<<(Tn * Tn) / 256, 256, 0, stream>>>(trans, E);
    lengths_kernel<<<Bn, 256, 0, stream>>>(mask, lengths);
    fused_fwd_kernel<<<Bn, 1024, 0, stream>>>(logits, start_t, end_t, trans, E,
                                              lengths, hist, den, last);
    numerator_kernel<<<Bn, 256, 0, stream>>>(logits, labels, start_t, end_t, trans,
                                             lengths, num);
    backtrack_kernel<<<Bn, 64, 0, stream>>>(hist, last, lengths, out);
    loss_kernel<<<1, 128, 0, stream>>>(num, den, out + (size_t)Bn * Sn);
}

// Round 2
// 1715.408 us; speedup vs baseline: 1.7072x; 1.7072x over previous
//
#include <hip/hip_runtime.h>
#include <hip/hip_bf16.h>
#include <math.h>

#define Bn 128
#define Sn 512
#define Tn 256

// ===================================================================
// FAST PATH (needs ~68 MB workspace): register-resident transition
// tables, max-only Viterbi forward + exact-equality backtrack,
// vit/den concurrent on disjoint blocks.
// ===================================================================

// E = exp(trans) fp32, transT = trans^T
__global__ void setup_kernel(const float* __restrict__ trans, float* __restrict__ E,
                             float* __restrict__ transT) {
    int k = blockIdx.x * blockDim.x + threadIdx.x;   // 65536 threads
    float v = trans[k];
    E[k] = __expf(v);
    transT[(k & 255) * 256 + (k >> 8)] = v;
}

// ---------------- lengths from mask (dtype auto-detect) ----------------
__global__ void lengths_kernel(const void* __restrict__ mask, int* __restrict__ lengths) {
    int b = blockIdx.x, tid = threadIdx.x;   // 256 threads
    const unsigned int* mu = (const unsigned int*)mask;
    unsigned int w0 = mu[0];
    int cnt = 0;
    if (w0 == 1u) {                       // int32 0/1 layout
        const int* mi = (const int*)mask;
        for (int t = tid; t < Sn; t += 256) cnt += (mi[b * Sn + t] != 0);
    } else if (w0 == 0x3F800000u) {       // float32 0/1 layout
        const float* mf = (const float*)mask;
        for (int t = tid; t < Sn; t += 256) cnt += (mf[b * Sn + t] != 0.0f);
    } else {                              // 1-byte bool layout
        const unsigned char* mb = (const unsigned char*)mask;
        for (int t = tid; t < Sn; t += 256) cnt += (mb[b * Sn + t] != 0);
    }
    for (int off = 32; off; off >>= 1) cnt += __shfl_xor(cnt, off);
    __shared__ int red[4];
    if ((tid & 63) == 0) red[tid >> 6] = cnt;
    __syncthreads();
    if (tid == 0) lengths[b] = red[0] + red[1] + red[2] + red[3];
}

// ---------------- numerator (gold path score) ----------------
__global__ void numerator_kernel(const float* __restrict__ logits, const int* __restrict__ labels,
                                 const float* __restrict__ start_t, const float* __restrict__ end_t,
                                 const float* __restrict__ trans, const int* __restrict__ lengths,
                                 float* __restrict__ num) {
    int b = blockIdx.x, tid = threadIdx.x;   // 256 threads
    int len = lengths[b];
    float acc = 0.0f;
    for (int t = tid + 1; t < len; t += 256) {
        int prev = labels[b * Sn + t - 1], cur = labels[b * Sn + t];
        acc += trans[prev * Tn + cur] + logits[((size_t)b * Sn + t) * Tn + cur];
    }
    for (int off = 32; off; off >>= 1) acc += __shfl_xor(acc, off);
    __shared__ float red[4];
    if ((tid & 63) == 0) red[tid >> 6] = acc;
    __syncthreads();
    if (tid == 0) {
        int l0 = labels[b * Sn];
        int ll = labels[b * Sn + len - 1];
        num[b] = start_t[l0] + logits[(size_t)b * Sn * Tn + l0]
               + red[0] + red[1] + red[2] + red[3] + end_t[ll];
    }
}

// ---------------- mega kernel: blocks 0..127 Viterbi fwd, 128..255 denominator ----------------
__launch_bounds__(256, 1)
__global__ void crf_fwd_kernel(const float* __restrict__ logits,
                               const float* __restrict__ start_t,
                               const float* __restrict__ end_t,
                               const float* __restrict__ trans,
                               const float* __restrict__ E,
                               const int* __restrict__ lengths,
                               float* __restrict__ hist,      // [S][B][T] best-value history
                               float* __restrict__ den_out,
                               int* __restrict__ last_out) {
    const int bid = blockIdx.x;
    const bool is_vit = bid < Bn;
    const int b = is_vit ? bid : bid - Bn;
    const int j = threadIdx.x;
    const int wave = j >> 6, lane = j & 63;
    const int len = lengths[b];

    __shared__ __align__(16) float sbuf[Tn];
    __shared__ float wred[4];
    __shared__ float redv[4];
    __shared__ int   redi[4];

    // per-thread column of the transition table (trans for vit, exp(trans) for den)
    float tab[Tn];
    {
        const float* src = (is_vit ? trans : E) + j;
        #pragma unroll
        for (int i = 0; i < Tn; ++i) tab[i] = src[(size_t)i * Tn];
    }

    const float* lg = logits + (size_t)b * Sn * Tn + j;
    float cur = start_t[j] + lg[0];
    float emit_next = lg[Tn];            // row t=1 (len >= 2 always)

    sbuf[j] = cur;
    __syncthreads();

    if (is_vit) {
        for (int t = 1; t < len; ++t) {
            float emit = emit_next;
            int tn = (t + 1 < len) ? (t + 1) : (len - 1);
            emit_next = lg[(size_t)tn * Tn];

            float best = -INFINITY;
            #pragma unroll
            for (int i = 0; i < Tn; i += 4) {
                float4 s4 = *(const float4*)(sbuf + i);
                float c0 = s4.x + tab[i];
                float c1 = s4.y + tab[i + 1];
                float c2 = s4.z + tab[i + 2];
                float c3 = s4.w + tab[i + 3];
                best = fmaxf(fmaxf(best, c0), c1);   // v_max3
                best = fmaxf(fmaxf(best, c2), c3);   // v_max3
            }
            hist[((size_t)t * Bn + b) * Tn + j] = best;   // pre-emit max value
            cur = best + emit;
            __syncthreads();            // all reads of sbuf done
            sbuf[j] = cur;
            __syncthreads();            // new state visible
        }
        // last = argmax_j(cur + end_t[j]), ties -> smallest j
        float bv = cur + end_t[j]; int bj = j;
        #pragma unroll
        for (int off = 32; off; off >>= 1) {
            float ov = __shfl_xor(bv, off);
            int   oj = __shfl_xor(bj, off);
            if (ov > bv || (ov == bv && oj < bj)) { bv = ov; bj = oj; }
        }
        if (lane == 0) { redv[wave] = bv; redi[wave] = bj; }
        __syncthreads();
        if (j == 0) {
            float BB = redv[0]; int AA = redi[0];
            #pragma unroll
            for (int w = 1; w < 4; ++w)
                if (redv[w] > BB || (redv[w] == BB && redi[w] < AA)) { BB = redv[w]; AA = redi[w]; }
            last_out[b] = AA;
        }
    } else {
        for (int t = 1; t < len; ++t) {
            float emit = emit_next;
            int tn = (t + 1 < len) ? (t + 1) : (len - 1);
            emit_next = lg[(size_t)tn * Tn];

            // m = max_j cur (global max, stable enough: at least one p == 1)
            float wm = cur;
            #pragma unroll
            for (int off = 32; off; off >>= 1) wm = fmaxf(wm, __shfl_xor(wm, off));
            if (lane == 0) wred[wave] = wm;
            __syncthreads();            // wred ready; prior-iter sbuf reads done
            float m = fmaxf(fmaxf(wred[0], wred[1]), fmaxf(wred[2], wred[3]));
            sbuf[j] = __expf(cur - m);
            __syncthreads();            // p visible

            float s0 = 0.f, s1 = 0.f, s2 = 0.f, s3 = 0.f;
            #pragma unroll
            for (int i = 0; i < Tn; i += 4) {
                float4 p4 = *(const float4*)(sbuf + i);
                s0 = fmaf(p4.x, tab[i],     s0);
                s1 = fmaf(p4.y, tab[i + 1], s1);
                s2 = fmaf(p4.z, tab[i + 2], s2);
                s3 = fmaf(p4.w, tab[i + 3], s3);
            }
            cur = m + __logf((s0 + s1) + (s2 + s3)) + emit;
        }
        // den = logsumexp_j(cur + end_t[j])
        float v2 = cur + end_t[j];
        float wm = v2;
        #pragma unroll
        for (int off = 32; off; off >>= 1) wm = fmaxf(wm, __shfl_xor(wm, off));
        if (lane == 0) wred[wave] = wm;
        __syncthreads();
        float M = fmaxf(fmaxf(wred[0], wred[1]), fmaxf(wred[2], wred[3]));
        float ex = __expf(v2 - M);
        #pragma unroll
        for (int off = 32; off; off >>= 1) ex += __shfl_xor(ex, off);
        if (lane == 0) redv[wave] = ex;
        __syncthreads();
        if (j == 0) den_out[b] = M + __logf(redv[0] + redv[1] + redv[2] + redv[3]);
    }
}

// ---------------- equality backtrack: one wave per batch ----------------
__global__ void crf_bt_kernel(const float* __restrict__ hist,
                              const float* __restrict__ logits,
                              const float* __restrict__ start_t,
                              const float* __restrict__ transT,
                              const int* __restrict__ last,
                              const int* __restrict__ lengths,
                              float* __restrict__ pred) {
    const int b = blockIdx.x, lane = threadIdx.x;   // 64 threads
    const int len = lengths[b], len1 = len - 1;
    __shared__ int tg[Sn];
    int tag = last[b];
    if (lane == 0) tg[len1] = tag;
    float target = hist[((size_t)len1 * Bn + b) * Tn + tag];

    const float4* lgrow = (const float4*)(logits + (size_t)b * Sn * Tn) + lane;
    float4 s4 = *((const float4*)start_t + lane);

    float4 hbuf[4], ebuf[4];
    #pragma unroll
    for (int q = 0; q < 4; ++q) {
        int r = len1 - 1 - q;
        if (r >= 0) {
            int rh = (r > 1) ? r : 1;
            ebuf[q] = lgrow[(size_t)r * 64];
            hbuf[q] = *((const float4*)(hist + ((size_t)rh * Bn + b) * Tn) + lane);
        }
    }

    for (int k = 0; k < len1; ++k) {
        int r = len1 - 1 - k;               // previous-time row index
        float4 h4 = hbuf[k & 3], e4 = ebuf[k & 3];
        float4 sv;
        if (r > 0) {
            sv.x = h4.x + e4.x; sv.y = h4.y + e4.y; sv.z = h4.z + e4.z; sv.w = h4.w + e4.w;
        } else {
            sv.x = s4.x + e4.x; sv.y = s4.y + e4.y; sv.z = s4.z + e4.z; sv.w = s4.w + e4.w;
        }
        int rp = r - 4;                      // prefetch 4 steps ahead
        if (rp >= 0) {
            int rh = (rp > 1) ? rp : 1;
            ebuf[k & 3] = lgrow[(size_t)rp * 64];
            hbuf[k & 3] = *((const float4*)(hist + ((size_t)rh * Bn + b) * Tn) + lane);
        }
        float4 t4 = *((const float4*)(transT + (size_t)tag * Tn) + lane);
        int m4 = ((sv.x + t4.x) == target ? 1 : 0)
               | ((sv.y + t4.y) == target ? 2 : 0)
               | ((sv.z + t4.z) == target ? 4 : 0)
               | ((sv.w + t4.w) == target ? 8 : 0);
        unsigned long long bal = __ballot(m4 != 0);
        int L = __ffsll(bal) - 1;
        int mm = __shfl(m4, L);
        int slot = __ffs(mm) - 1;
        tag = L * 4 + slot;
        if (lane == 0) tg[r] = tag;
        float hv = (slot == 0) ? h4.x : (slot == 1) ? h4.y : (slot == 2) ? h4.z : h4.w;
        target = __shfl(hv, L);              // hist[r][tag], valid when r > 0
    }
    __syncthreads();
    for (int t = lane; t < Sn; t += 64)
        pred[(size_t)b * Sn + t] = (t < len) ? (float)tg[t] : 0.0f;
}

// ---------------- loss = mean(den - num) ----------------
__global__ void loss_kernel(const float* __restrict__ num, const float* __restrict__ den,
                            float* __restrict__ out_loss) {
    int tid = threadIdx.x;   // 128 threads
    float v = den[tid] - num[tid];
    for (int off = 32; off; off >>= 1) v += __shfl_xor(v, off);
    __shared__ float r2[2];
    if ((tid & 63) == 0) r2[tid >> 6] = v;
    __syncthreads();
    if (tid == 0) out_loss[0] = (r2[0] + r2[1]) * (1.0f / 128.0f);
}

// ===================================================================
// FALLBACK PATH (round-1, proven): used only if ws_size is too small
// ===================================================================

__global__ void compute_E_kernel(const float* __restrict__ trans, __hip_bfloat16* __restrict__ E) {
    int k = blockIdx.x * blockDim.x + threadIdx.x;
    if (k < Tn * Tn) E[k] = __float2bfloat16(__expf(trans[k]));
}

__launch_bounds__(1024)
__global__ void fused_fwd_kernel(const float* __restrict__ logits,
                                 const float* __restrict__ start_t,
                                 const float* __restrict__ end_t,
                                 const float* __restrict__ trans,
                                 const __hip_bfloat16* __restrict__ E,
                                 const int* __restrict__ lengths,
                                 unsigned char* __restrict__ hist,
                                 float* __restrict__ den_out,
                                 int* __restrict__ last_out) {
    int b = blockIdx.x;
    int tid = threadIdx.x;
    int j = tid & 255;
    int h = tid >> 8;
    int i0 = h * 64;

    __shared__ __align__(16) float sden[Tn];
    __shared__ __align__(16) float svit[Tn];
    __shared__ __align__(16) float p[Tn];
    __shared__ float redf[16];
    __shared__ float reds[16];
    __shared__ float redb[16];
    __shared__ int   redbi[16];
    __shared__ float pd[1024];
    __shared__ float pv[1024];
    __shared__ int   pa[1024];

    int len = lengths[b];
    if (tid < Tn) {
        float v = start_t[j] + logits[(size_t)b * Sn * Tn + j];
        sden[j] = v;
        svit[j] = v;
    }
    __syncthreads();

    for (int t = 1; t < len; ++t) {
        float v = sden[j];
        for (int off = 32; off; off >>= 1) v = fmaxf(v, __shfl_xor(v, off));
        if ((tid & 63) == 0) redf[tid >> 6] = v;
        __syncthreads();
        float m = redf[0];
        #pragma unroll
        for (int w = 1; w < 16; ++w) m = fmaxf(m, redf[w]);
        if (tid < Tn) p[j] = __expf(sden[j] - m);
        __syncthreads();

        float s = 0.0f, best = -INFINITY;
        int arg = 0;
        const float* tr = trans + (size_t)i0 * Tn + j;
        const __hip_bfloat16* er = E + (size_t)i0 * Tn + j;
        #pragma unroll 4
        for (int i = i0; i < i0 + 64; i += 4) {
            float4 p4  = *(const float4*)(p + i);
            float4 sv4 = *(const float4*)(svit + i);
            float tr0 = tr[0 * Tn], tr1 = tr[1 * Tn], tr2 = tr[2 * Tn], tr3 = tr[3 * Tn];
            float e0 = __bfloat162float(er[0 * Tn]);
            float e1 = __bfloat162float(er[1 * Tn]);
            float e2 = __bfloat162float(er[2 * Tn]);
            float e3 = __bfloat162float(er[3 * Tn]);
            tr += 4 * Tn; er += 4 * Tn;
            s = fmaf(p4.x, e0, s); s = fmaf(p4.y, e1, s);
            s = fmaf(p4.z, e2, s); s = fmaf(p4.w, e3, s);
            float c0 = sv4.x + tr0; if (c0 > best) { best = c0; arg = i + 0; }
            float c1 = sv4.y + tr1; if (c1 > best) { best = c1; arg = i + 1; }
            float c2 = sv4.z + tr2; if (c2 > best) { best = c2; arg = i + 2; }
            float c3 = sv4.w + tr3; if (c3 > best) { best = c3; arg = i + 3; }
        }
        pd[tid] = s; pv[tid] = best; pa[tid] = arg;
        __syncthreads();

        if (tid < Tn) {
            float ss = pd[j] + pd[j + 256] + pd[j + 512] + pd[j + 768];
            float bb = pv[j]; int aa = pa[j];
            if (pv[j + 256] > bb) { bb = pv[j + 256]; aa = pa[j + 256]; }
            if (pv[j + 512] > bb) { bb = pv[j + 512]; aa = pa[j + 512]; }
            if (pv[j + 768] > bb) { bb = pv[j + 768]; aa = pa[j + 768]; }
            float emit = logits[((size_t)b * Sn + t) * Tn + j];
            sden[j] = m + __logf(ss) + emit;
            svit[j] = bb + emit;
            hist[((size_t)t * Bn + b) * Tn + j] = (unsigned char)aa;
        }
        __syncthreads();
    }

    float v2d = sden[j] + end_t[j];
    float M = v2d;
    for (int off = 32; off; off >>= 1) M = fmaxf(M, __shfl_xor(M, off));
    if ((tid & 63) == 0) redf[tid >> 6] = M;
    __syncthreads();
    M = redf[0];
    #pragma unroll
    for (int w = 1; w < 16; ++w) M = fmaxf(M, redf[w]);

    float ex = (tid < Tn) ? __expf(v2d - M) : 0.0f;
    for (int off = 32; off; off >>= 1) ex += __shfl_xor(ex, off);

    float v2v = svit[j] + end_t[j];
    float bv = v2v; int bj = j;
    for (int off = 32; off; off >>= 1) {
        float ov = __shfl_xor(bv, off); int oj = __shfl_xor(bj, off);
        if (ov > bv || (ov == bv && oj < bj)) { bv = ov; bj = oj; }
    }
    if ((tid & 63) == 0) { reds[tid >> 6] = ex; redb[tid >> 6] = bv; redbi[tid >> 6] = bj; }
    __syncthreads();
    if (tid == 0) {
        float sum = 0.0f;
        #pragma unroll
        for (int w = 0; w < 16; ++w) sum += reds[w];
        den_out[b] = M + __logf(sum);
        float BB = redb[0]; int AA = redbi[0];
        #pragma unroll
        for (int w = 1; w < 16; ++w)
            if (redb[w] > BB || (redb[w] == BB && redbi[w] < AA)) { BB = redb[w]; AA = redbi[w]; }
        last_out[b] = AA;
    }
}

__global__ void backtrack_kernel(const unsigned char* __restrict__ hist,
                                 const int* __restrict__ last,
                                 const int* __restrict__ lengths,
                                 float* __restrict__ pred) {
    int b = blockIdx.x, lane = threadIdx.x;
    int len = lengths[b];
    int len1 = len - 1;
    __shared__ int tg[Sn];
    int tag = last[b];

    const int P = 16;
    unsigned int buf[P];
    #pragma unroll
    for (int q = 0; q < P; ++q) {
        int r = len1 - q;
        if (q < len1)
            buf[q] = *(const unsigned int*)(hist + ((size_t)r * Bn + b) * Tn + lane * 4);
    }
    if (lane == 0) tg[len1] = tag;
    for (int q = 0; q < len1; ++q) {
        unsigned int w = buf[q & (P - 1)];
        int sel = __shfl((int)w, tag >> 2, 64);
        tag = (sel >> ((tag & 3) * 8)) & 255;
        int t = len1 - 1 - q;
        if (lane == 0) tg[t] = tag;
        int rn = len1 - q - P;
        if (rn >= 1)
            buf[q & (P - 1)] = *(const unsigned int*)(hist + ((size_t)rn * Bn + b) * Tn + lane * 4);
    }
    __syncthreads();
    for (int t = lane; t < Sn; t += 64)
        pred[(size_t)b * Sn + t] = (t < len) ? (float)tg[t] : 0.0f;
}

// ===================================================================

extern "C" void kernel_launch(void* const* d_in, const int* in_sizes, int n_in,
                              void* d_out, int out_size, void* d_ws, size_t ws_size,
                              hipStream_t stream) {
    const float* logits  = (const float*)d_in[0];
    const void*  mask    = d_in[1];
    const int*   labels  = (const int*)d_in[2];
    const float* start_t = (const float*)d_in[3];
    const float* end_t   = (const float*)d_in[4];
    const float* trans   = (const float*)d_in[5];
    float* out = (float*)d_out;   // [B*S] pred as float, then [1] loss

    char* ws = (char*)d_ws;
    const size_t histF = (size_t)Sn * Bn * Tn * 4;           // 67.1 MB fp32 best-value hist
    const size_t tblF  = (size_t)Tn * Tn * 4;                // 256 KB
    const size_t needF = histF + 2 * tblF + 8192;

    if (ws_size >= needF) {
        // -------- fast path --------
        float* hist    = (float*)ws;
        float* transT  = (float*)(ws + histF);
        float* E       = (float*)(ws + histF + tblF);
        char*  tail    = ws + histF + 2 * tblF;
        int*   lengths = (int*)tail;
        float* num     = (float*)(tail + 2048);
        float* den     = (float*)(tail + 4096);
        int*   lastp   = (int*)(tail + 6144);

        setup_kernel<<<Tn * Tn / 256, 256, 0, stream>>>(trans, E, transT);
        lengths_kernel<<<Bn, 256, 0, stream>>>(mask, lengths);
        crf_fwd_kernel<<<2 * Bn, 256, 0, stream>>>(logits, start_t, end_t, trans, E,
                                                   lengths, hist, den, lastp);
        numerator_kernel<<<Bn, 256, 0, stream>>>(logits, labels, start_t, end_t, trans,
                                                 lengths, num);
        crf_bt_kernel<<<Bn, 64, 0, stream>>>(hist, logits, start_t, transT, lastp, lengths, out);
        loss_kernel<<<1, 128, 0, stream>>>(num, den, out + (size_t)Bn * Sn);
    } else {
        // -------- fallback: proven round-1 path (~17 MB ws) --------
        const size_t histSz = (size_t)Sn * Bn * Tn;
        unsigned char*  hist    = (unsigned char*)ws;
        int*            lengths = (int*)(ws + histSz);
        float*          num     = (float*)(ws + histSz + 512);
        float*          den     = (float*)(ws + histSz + 1024);
        int*            lastp   = (int*)(ws + histSz + 1536);
        __hip_bfloat16* E       = (__hip_bfloat16*)(ws + histSz + 2048);

        compute_E_kernel<<<(Tn * Tn) / 256, 256, 0, stream>>>(trans, E);
        lengths_kernel<<<Bn, 256, 0, stream>>>(mask, lengths);
        fused_fwd_kernel<<<Bn, 1024, 0, stream>>>(logits, start_t, end_t, trans, E,
                                                  lengths, hist, den, lastp);
        numerator_kernel<<<Bn, 256, 0, stream>>>(logits, labels, start_t, end_t, trans,
                                                 lengths, num);
        backtrack_kernel<<<Bn, 64, 0, stream>>>(hist, lastp, lengths, out);
        loss_kernel<<<1, 128, 0, stream>>>(num, den, out + (size_t)Bn * Sn);
    }
}

// Round 3
// 796.487 us; speedup vs baseline: 3.6767x; 2.1537x over previous
//
#include <hip/hip_runtime.h>
#include <hip/hip_bf16.h>
#include <math.h>

#define Bn 128
#define Sn 512
#define Tn 256

typedef float vf64 __attribute__((ext_vector_type(64)));

// ===================================================================
// FAST PATH
// ===================================================================

// transT = trans^T (for backtrack)
__global__ void prep_kernel(const float* __restrict__ trans, float* __restrict__ transT) {
    int k = blockIdx.x * blockDim.x + threadIdx.x;   // 65536 threads
    transT[(k & 255) * 256 + (k >> 8)] = trans[k];
}

// blocks 0..127: Viterbi forward (batch b). blocks 128..255: denominator + numerator (batch b-128).
// 512 threads: jp = tid&127 -> columns j0=2jp, j1=2jp+1 ; q = tid>>7 -> i in [64q, 64q+64)
__launch_bounds__(512, 2)
__global__ void crf_fwd2_kernel(const float* __restrict__ logits,
                                const float* __restrict__ start_t,
                                const float* __restrict__ end_t,
                                const float* __restrict__ trans,
                                const void* __restrict__ mask,
                                const int* __restrict__ labels,
                                int* __restrict__ lengths_out,
                                float* __restrict__ hist,      // [S][B][T] pre-emit best values
                                float* __restrict__ den_out,
                                int* __restrict__ last_out,
                                float* __restrict__ num_out) {
    const int bid = blockIdx.x;
    const bool is_vit = bid < Bn;
    const int b = is_vit ? bid : bid - Bn;
    const int tid = threadIdx.x;
    const int jp = tid & 127;
    const int q  = tid >> 7;          // i-quarter 0..3
    const int j0 = jp * 2, j1 = j0 + 1;
    const int i0 = q * 64;
    const int wv = tid >> 6, lane = tid & 63;

    __shared__ __align__(16) float sbuf[Tn];     // state (vit) / p (den)
    __shared__ float part[1024];                 // per-(quarter,column) partials
    __shared__ float msh[2];
    __shared__ int   lenred[8];
    __shared__ float wredf[8];
    __shared__ int   wredi[8];
    __shared__ float wnum[8];

    // ---- per-block length from mask (dtype auto-detect) ----
    int nz;
    {
        const unsigned int* mu = (const unsigned int*)mask;
        unsigned int w0 = mu[0];
        if (w0 == 1u)                nz = (((const int*)mask)[b * Sn + tid] != 0);
        else if (w0 == 0x3F800000u)  nz = (((const float*)mask)[b * Sn + tid] != 0.0f);
        else                         nz = (((const unsigned char*)mask)[b * Sn + tid] != 0);
    }
    unsigned long long bal = __ballot(nz != 0);
    if (lane == 0) lenred[wv] = __popcll(bal);
    __syncthreads();
    int len = 0;
    #pragma unroll
    for (int w = 0; w < 8; ++w) len += lenred[w];
    if (is_vit && tid == 0) lengths_out[b] = len;

    // ---- per-thread transition columns in registers (SSA vectors, no alloca) ----
    vf64 tA, tB;
    {
        const float2* t2 = (const float2*)trans;
        if (is_vit) {
            #pragma unroll
            for (int i = 0; i < 64; ++i) {
                float2 v = t2[(size_t)(i0 + i) * 128 + jp];
                tA[i] = v.x; tB[i] = v.y;
            }
        } else {
            #pragma unroll
            for (int i = 0; i < 64; ++i) {
                float2 v = t2[(size_t)(i0 + i) * 128 + jp];
                tA[i] = __expf(v.x); tB[i] = __expf(v.y);
            }
        }
    }

    const float* lg = logits + (size_t)b * Sn * Tn + tid;   // valid for tid<256 use
    const float4* sb4 = (const float4*)sbuf;
    const int q16 = q * 16;

    float cur = 0.0f, emit_cur = 0.0f, emit_next = 0.0f, base = 0.0f;

    if (is_vit) {
        // ================= Viterbi =================
        if (tid < Tn) {
            cur = start_t[tid] + lg[0];
            sbuf[tid] = cur;
            emit_cur = lg[Tn];          // emit for t=1
        }
        __syncthreads();

        for (int t = 1; t < len; ++t) {
            if (tid < Tn) {             // prefetch next emit
                int tn = (t + 1 < len) ? (t + 1) : (len - 1);
                emit_next = lg[(size_t)tn * Tn];
            }
            // phase 1: partial max over my i-quarter for my 2 columns
            float b0 = -INFINITY, b1 = -INFINITY, b2 = -INFINITY, b3 = -INFINITY;
            #pragma unroll
            for (int k = 0; k < 16; ++k) {
                float4 s4 = sb4[q16 + k];
                int i = 4 * k;
                float c0 = s4.x + tA[i],     c1 = s4.y + tA[i + 1];
                float c2 = s4.z + tA[i + 2], c3 = s4.w + tA[i + 3];
                b0 = fmaxf(fmaxf(b0, c0), c1);
                b1 = fmaxf(fmaxf(b1, c2), c3);
                float d0 = s4.x + tB[i],     d1 = s4.y + tB[i + 1];
                float d2 = s4.z + tB[i + 2], d3 = s4.w + tB[i + 3];
                b2 = fmaxf(fmaxf(b2, d0), d1);
                b3 = fmaxf(fmaxf(b3, d2), d3);
            }
            part[q * 256 + j0] = fmaxf(b0, b1);
            part[q * 256 + j1] = fmaxf(b2, b3);
            __syncthreads();
            // phase 2: combine quarters, store hist, advance state
            if (tid < Tn) {
                float bb = fmaxf(fmaxf(part[tid], part[256 + tid]),
                                 fmaxf(part[512 + tid], part[768 + tid]));
                hist[((size_t)t * Bn + b) * Tn + tid] = bb;
                cur = bb + emit_cur;
                emit_cur = emit_next;
                sbuf[tid] = cur;
            }
            __syncthreads();
        }

        // epilogue: last = argmax_j(cur + end_t[j]), ties -> smallest j
        float bv = -INFINITY; int bj = 0;
        if (tid < Tn) { bv = cur + end_t[tid]; bj = tid; }
        #pragma unroll
        for (int off = 32; off; off >>= 1) {
            float ov = __shfl_xor(bv, off);
            int   oj = __shfl_xor(bj, off);
            if (ov > bv || (ov == bv && oj < bj)) { bv = ov; bj = oj; }
        }
        if (lane == 0) { wredf[wv] = bv; wredi[wv] = bj; }
        __syncthreads();
        if (tid == 0) {
            float BB = wredf[0]; int AA = wredi[0];
            #pragma unroll
            for (int w = 1; w < 4; ++w)
                if (wredf[w] > BB || (wredf[w] == BB && wredi[w] < AA)) { BB = wredf[w]; AA = wredi[w]; }
            last_out[b] = AA;
        }
    } else {
        // ================= denominator (lagged-base logsumexp) =================
        if (tid < Tn) {
            cur = start_t[tid] + lg[0];
            if (tid == 0) msh[0] = cur;
            emit_cur = lg[Tn];
        }
        __syncthreads();
        if (tid < Tn) {
            base = msh[0];
            sbuf[tid] = __expf(cur - base);
        }
        __syncthreads();

        for (int t = 1; t < len; ++t) {
            if (tid < Tn) {
                int tn = (t + 1 < len) ? (t + 1) : (len - 1);
                emit_next = lg[(size_t)tn * Tn];
            }
            // phase 1: partial dot(p, E) over my quarter for my 2 columns
            float a0 = 0.f, a1 = 0.f, c0 = 0.f, c1 = 0.f;
            #pragma unroll
            for (int k = 0; k < 16; ++k) {
                float4 p4 = sb4[q16 + k];
                int i = 4 * k;
                a0 = fmaf(p4.x, tA[i],     a0); a1 = fmaf(p4.y, tA[i + 1], a1);
                a0 = fmaf(p4.z, tA[i + 2], a0); a1 = fmaf(p4.w, tA[i + 3], a1);
                c0 = fmaf(p4.x, tB[i],     c0); c1 = fmaf(p4.y, tB[i + 1], c1);
                c0 = fmaf(p4.z, tB[i + 2], c0); c1 = fmaf(p4.w, tB[i + 3], c1);
            }
            part[q * 256 + j0] = a0 + a1;
            part[q * 256 + j1] = c0 + c1;
            __syncthreads();
            // phase 2: combine, log, re-exponentiate with lagged base
            if (tid < Tn) {
                float tot = (part[tid] + part[256 + tid]) + (part[512 + tid] + part[768 + tid]);
                float nb = msh[(t - 1) & 1];            // cur_0 from two steps back (or init)
                cur = base + __logf(tot) + emit_cur;
                emit_cur = emit_next;
                sbuf[tid] = __expf(cur - nb);
                base = nb;
                if (tid == 0) msh[t & 1] = cur;
            }
            __syncthreads();
        }

        // epilogue: den = logsumexp_j(cur + end_t[j]) (exact)
        float v2 = (tid < Tn) ? (cur + end_t[tid]) : -INFINITY;
        float wm = v2;
        #pragma unroll
        for (int off = 32; off; off >>= 1) wm = fmaxf(wm, __shfl_xor(wm, off));
        if (lane == 0) wredf[wv] = wm;
        __syncthreads();
        float M = fmaxf(fmaxf(wredf[0], wredf[1]), fmaxf(wredf[2], wredf[3]));
        float ex = (tid < Tn) ? __expf(v2 - M) : 0.0f;
        #pragma unroll
        for (int off = 32; off; off >>= 1) ex += __shfl_xor(ex, off);
        if (lane == 0) wnum[wv] = ex;
        __syncthreads();
        if (tid == 0) den_out[b] = M + __logf(wnum[0] + wnum[1] + wnum[2] + wnum[3]);
        __syncthreads();

        // ================= numerator (fused; vit blocks are the wall) =================
        float acc = 0.0f;
        if (tid >= 1 && tid < len) {
            int prev = labels[b * Sn + tid - 1], curl = labels[b * Sn + tid];
            acc = trans[prev * Tn + curl] + logits[((size_t)b * Sn + tid) * Tn + curl];
        }
        #pragma unroll
        for (int off = 32; off; off >>= 1) acc += __shfl_xor(acc, off);
        if (lane == 0) wnum[wv] = acc;
        __syncthreads();
        if (tid == 0) {
            float s = 0.0f;
            #pragma unroll
            for (int w = 0; w < 8; ++w) s += wnum[w];
            int l0 = labels[b * Sn];
            int ll = labels[b * Sn + len - 1];
            num_out[b] = start_t[l0] + logits[(size_t)b * Sn * Tn + l0] + s + end_t[ll];
        }
    }
}

// ---------------- equality backtrack (blocks 0..127) + loss (block 128) ----------------
__global__ void bt_loss_kernel(const float* __restrict__ hist,
                               const float* __restrict__ logits,
                               const float* __restrict__ start_t,
                               const float* __restrict__ transT,
                               const int* __restrict__ last,
                               const int* __restrict__ lengths,
                               const float* __restrict__ num,
                               const float* __restrict__ den,
                               float* __restrict__ pred,
                               float* __restrict__ out_loss) {
    const int lane = threadIdx.x;   // 64 threads
    if (blockIdx.x == Bn) {
        float v = (den[lane] - num[lane]) + (den[lane + 64] - num[lane + 64]);
        #pragma unroll
        for (int off = 32; off; off >>= 1) v += __shfl_xor(v, off);
        if (lane == 0) out_loss[0] = v * (1.0f / 128.0f);
        return;
    }
    const int b = blockIdx.x;
    const int len = lengths[b], len1 = len - 1;
    __shared__ int tg[Sn];
    int tag = last[b];
    if (lane == 0) tg[len1] = tag;
    float target = hist[((size_t)len1 * Bn + b) * Tn + tag];

    const float4* lgrow = (const float4*)(logits + (size_t)b * Sn * Tn) + lane;
    float4 s4 = *((const float4*)start_t + lane);

    float4 hbuf[4], ebuf[4];
    #pragma unroll
    for (int qq = 0; qq < 4; ++qq) {
        int r = len1 - 1 - qq;
        if (r >= 0) {
            int rh = (r > 1) ? r : 1;
            ebuf[qq] = lgrow[(size_t)r * 64];
            hbuf[qq] = *((const float4*)(hist + ((size_t)rh * Bn + b) * Tn) + lane);
        }
    }

    for (int k = 0; k < len1; ++k) {
        int r = len1 - 1 - k;               // previous-time row index
        float4 h4 = hbuf[k & 3], e4 = ebuf[k & 3];
        float4 sv;
        if (r > 0) {
            sv.x = h4.x + e4.x; sv.y = h4.y + e4.y; sv.z = h4.z + e4.z; sv.w = h4.w + e4.w;
        } else {
            sv.x = s4.x + e4.x; sv.y = s4.y + e4.y; sv.z = s4.z + e4.z; sv.w = s4.w + e4.w;
        }
        int rp = r - 4;                      // prefetch 4 steps ahead
        if (rp >= 0) {
            int rh = (rp > 1) ? rp : 1;
            ebuf[k & 3] = lgrow[(size_t)rp * 64];
            hbuf[k & 3] = *((const float4*)(hist + ((size_t)rh * Bn + b) * Tn) + lane);
        }
        float4 t4 = *((const float4*)(transT + (size_t)tag * Tn) + lane);
        int m4 = ((sv.x + t4.x) == target ? 1 : 0)
               | ((sv.y + t4.y) == target ? 2 : 0)
               | ((sv.z + t4.z) == target ? 4 : 0)
               | ((sv.w + t4.w) == target ? 8 : 0);
        unsigned long long bb = __ballot(m4 != 0);
        int L = __ffsll(bb) - 1;
        int mm = __shfl(m4, L);
        int slot = __ffs(mm) - 1;
        tag = L * 4 + slot;
        if (lane == 0) tg[r] = tag;
        float hv = (slot == 0) ? h4.x : (slot == 1) ? h4.y : (slot == 2) ? h4.z : h4.w;
        target = __shfl(hv, L);              // hist[r][tag], valid when r > 0
    }
    __syncthreads();
    for (int t = lane; t < Sn; t += 64)
        pred[(size_t)b * Sn + t] = (t < len) ? (float)tg[t] : 0.0f;
}

// ===================================================================
// FALLBACK PATH (round-1, proven): used only if ws_size is too small
// ===================================================================

__global__ void compute_E_kernel(const float* __restrict__ trans, __hip_bfloat16* __restrict__ E) {
    int k = blockIdx.x * blockDim.x + threadIdx.x;
    if (k < Tn * Tn) E[k] = __float2bfloat16(__expf(trans[k]));
}

__global__ void lengths_kernel(const void* __restrict__ mask, int* __restrict__ lengths) {
    int b = blockIdx.x, tid = threadIdx.x;
    const unsigned int* mu = (const unsigned int*)mask;
    unsigned int w0 = mu[0];
    int cnt = 0;
    if (w0 == 1u) {
        const int* mi = (const int*)mask;
        for (int t = tid; t < Sn; t += 256) cnt += (mi[b * Sn + t] != 0);
    } else if (w0 == 0x3F800000u) {
        const float* mf = (const float*)mask;
        for (int t = tid; t < Sn; t += 256) cnt += (mf[b * Sn + t] != 0.0f);
    } else {
        const unsigned char* mb = (const unsigned char*)mask;
        for (int t = tid; t < Sn; t += 256) cnt += (mb[b * Sn + t] != 0);
    }
    for (int off = 32; off; off >>= 1) cnt += __shfl_xor(cnt, off);
    __shared__ int red[4];
    if ((tid & 63) == 0) red[tid >> 6] = cnt;
    __syncthreads();
    if (tid == 0) lengths[b] = red[0] + red[1] + red[2] + red[3];
}

__global__ void numerator_kernel(const float* __restrict__ logits, const int* __restrict__ labels,
                                 const float* __restrict__ start_t, const float* __restrict__ end_t,
                                 const float* __restrict__ trans, const int* __restrict__ lengths,
                                 float* __restrict__ num) {
    int b = blockIdx.x, tid = threadIdx.x;
    int len = lengths[b];
    float acc = 0.0f;
    for (int t = tid + 1; t < len; t += 256) {
        int prev = labels[b * Sn + t - 1], cur = labels[b * Sn + t];
        acc += trans[prev * Tn + cur] + logits[((size_t)b * Sn + t) * Tn + cur];
    }
    for (int off = 32; off; off >>= 1) acc += __shfl_xor(acc, off);
    __shared__ float red[4];
    if ((tid & 63) == 0) red[tid >> 6] = acc;
    __syncthreads();
    if (tid == 0) {
        int l0 = labels[b * Sn];
        int ll = labels[b * Sn + len - 1];
        num[b] = start_t[l0] + logits[(size_t)b * Sn * Tn + l0]
               + red[0] + red[1] + red[2] + red[3] + end_t[ll];
    }
}

__launch_bounds__(1024)
__global__ void fused_fwd_kernel(const float* __restrict__ logits,
                                 const float* __restrict__ start_t,
                                 const float* __restrict__ end_t,
                                 const float* __restrict__ trans,
                                 const __hip_bfloat16* __restrict__ E,
                                 const int* __restrict__ lengths,
                                 unsigned char* __restrict__ hist,
                                 float* __restrict__ den_out,
                                 int* __restrict__ last_out) {
    int b = blockIdx.x;
    int tid = threadIdx.x;
    int j = tid & 255;
    int h = tid >> 8;
    int i0 = h * 64;

    __shared__ __align__(16) float sden[Tn];
    __shared__ __align__(16) float svit[Tn];
    __shared__ __align__(16) float p[Tn];
    __shared__ float redf[16];
    __shared__ float reds[16];
    __shared__ float redb[16];
    __shared__ int   redbi[16];
    __shared__ float pd[1024];
    __shared__ float pv[1024];
    __shared__ int   pa[1024];

    int len = lengths[b];
    if (tid < Tn) {
        float v = start_t[j] + logits[(size_t)b * Sn * Tn + j];
        sden[j] = v;
        svit[j] = v;
    }
    __syncthreads();

    for (int t = 1; t < len; ++t) {
        float v = sden[j];
        for (int off = 32; off; off >>= 1) v = fmaxf(v, __shfl_xor(v, off));
        if ((tid & 63) == 0) redf[tid >> 6] = v;
        __syncthreads();
        float m = redf[0];
        #pragma unroll
        for (int w = 1; w < 16; ++w) m = fmaxf(m, redf[w]);
        if (tid < Tn) p[j] = __expf(sden[j] - m);
        __syncthreads();

        float s = 0.0f, best = -INFINITY;
        int arg = 0;
        const float* tr = trans + (size_t)i0 * Tn + j;
        const __hip_bfloat16* er = E + (size_t)i0 * Tn + j;
        #pragma unroll 4
        for (int i = i0; i < i0 + 64; i += 4) {
            float4 p4  = *(const float4*)(p + i);
            float4 sv4 = *(const float4*)(svit + i);
            float tr0 = tr[0 * Tn], tr1 = tr[1 * Tn], tr2 = tr[2 * Tn], tr3 = tr[3 * Tn];
            float e0 = __bfloat162float(er[0 * Tn]);
            float e1 = __bfloat162float(er[1 * Tn]);
            float e2 = __bfloat162float(er[2 * Tn]);
            float e3 = __bfloat162float(er[3 * Tn]);
            tr += 4 * Tn; er += 4 * Tn;
            s = fmaf(p4.x, e0, s); s = fmaf(p4.y, e1, s);
            s = fmaf(p4.z, e2, s); s = fmaf(p4.w, e3, s);
            float c0 = sv4.x + tr0; if (c0 > best) { best = c0; arg = i + 0; }
            float c1 = sv4.y + tr1; if (c1 > best) { best = c1; arg = i + 1; }
            float c2 = sv4.z + tr2; if (c2 > best) { best = c2; arg = i + 2; }
            float c3 = sv4.w + tr3; if (c3 > best) { best = c3; arg = i + 3; }
        }
        pd[tid] = s; pv[tid] = best; pa[tid] = arg;
        __syncthreads();

        if (tid < Tn) {
            float ss = pd[j] + pd[j + 256] + pd[j + 512] + pd[j + 768];
            float bb = pv[j]; int aa = pa[j];
            if (pv[j + 256] > bb) { bb = pv[j + 256]; aa = pa[j + 256]; }
            if (pv[j + 512] > bb) { bb = pv[j + 512]; aa = pa[j + 512]; }
            if (pv[j + 768] > bb) { bb = pv[j + 768]; aa = pa[j + 768]; }
            float emit = logits[((size_t)b * Sn + t) * Tn + j];
            sden[j] = m + __logf(ss) + emit;
            svit[j] = bb + emit;
            hist[((size_t)t * Bn + b) * Tn + j] = (unsigned char)aa;
        }
        __syncthreads();
    }

    float v2d = sden[j] + end_t[j];
    float M = v2d;
    for (int off = 32; off; off >>= 1) M = fmaxf(M, __shfl_xor(M, off));
    if ((tid & 63) == 0) redf[tid >> 6] = M;
    __syncthreads();
    M = redf[0];
    #pragma unroll
    for (int w = 1; w < 16; ++w) M = fmaxf(M, redf[w]);

    float ex = (tid < Tn) ? __expf(v2d - M) : 0.0f;
    for (int off = 32; off; off >>= 1) ex += __shfl_xor(ex, off);

    float v2v = svit[j] + end_t[j];
    float bv = v2v; int bj = j;
    for (int off = 32; off; off >>= 1) {
        float ov = __shfl_xor(bv, off); int oj = __shfl_xor(bj, off);
        if (ov > bv || (ov == bv && oj < bj)) { bv = ov; bj = oj; }
    }
    if ((tid & 63) == 0) { reds[tid >> 6] = ex; redb[tid >> 6] = bv; redbi[tid >> 6] = bj; }
    __syncthreads();
    if (tid == 0) {
        float sum = 0.0f;
        #pragma unroll
        for (int w = 0; w < 16; ++w) sum += reds[w];
        den_out[b] = M + __logf(sum);
        float BB = redb[0]; int AA = redbi[0];
        #pragma unroll
        for (int w = 1; w < 16; ++w)
            if (redb[w] > BB || (redb[w] == BB && redbi[w] < AA)) { BB = redb[w]; AA = redbi[w]; }
        last_out[b] = AA;
    }
}

__global__ void backtrack_kernel(const unsigned char* __restrict__ hist,
                                 const int* __restrict__ last,
                                 const int* __restrict__ lengths,
                                 float* __restrict__ pred) {
    int b = blockIdx.x, lane = threadIdx.x;
    int len = lengths[b];
    int len1 = len - 1;
    __shared__ int tg[Sn];
    int tag = last[b];

    const int P = 16;
    unsigned int buf[P];
    #pragma unroll
    for (int qq = 0; qq < P; ++qq) {
        int r = len1 - qq;
        if (qq < len1)
            buf[qq] = *(const unsigned int*)(hist + ((size_t)r * Bn + b) * Tn + lane * 4);
    }
    if (lane == 0) tg[len1] = tag;
    for (int qq = 0; qq < len1; ++qq) {
        unsigned int w = buf[qq & (P - 1)];
        int sel = __shfl((int)w, tag >> 2, 64);
        tag = (sel >> ((tag & 3) * 8)) & 255;
        int t = len1 - 1 - qq;
        if (lane == 0) tg[t] = tag;
        int rn = len1 - qq - P;
        if (rn >= 1)
            buf[qq & (P - 1)] = *(const unsigned int*)(hist + ((size_t)rn * Bn + b) * Tn + lane * 4);
    }
    __syncthreads();
    for (int t = lane; t < Sn; t += 64)
        pred[(size_t)b * Sn + t] = (t < len) ? (float)tg[t] : 0.0f;
}

__global__ void loss_kernel(const float* __restrict__ num, const float* __restrict__ den,
                            float* __restrict__ out_loss) {
    int tid = threadIdx.x;
    float v = den[tid] - num[tid];
    for (int off = 32; off; off >>= 1) v += __shfl_xor(v, off);
    __shared__ float r2[2];
    if ((tid & 63) == 0) r2[tid >> 6] = v;
    __syncthreads();
    if (tid == 0) out_loss[0] = (r2[0] + r2[1]) * (1.0f / 128.0f);
}

// ===================================================================

extern "C" void kernel_launch(void* const* d_in, const int* in_sizes, int n_in,
                              void* d_out, int out_size, void* d_ws, size_t ws_size,
                              hipStream_t stream) {
    const float* logits  = (const float*)d_in[0];
    const void*  mask    = d_in[1];
    const int*   labels  = (const int*)d_in[2];
    const float* start_t = (const float*)d_in[3];
    const float* end_t   = (const float*)d_in[4];
    const float* trans   = (const float*)d_in[5];
    float* out = (float*)d_out;   // [B*S] pred as float, then [1] loss

    char* ws = (char*)d_ws;
    const size_t histF = (size_t)Sn * Bn * Tn * 4;           // 67.1 MB fp32 best-value hist
    const size_t tblF  = (size_t)Tn * Tn * 4;                // 256 KB
    const size_t needF = histF + tblF + 8192;

    if (ws_size >= needF) {
        // -------- fast path --------
        float* hist    = (float*)ws;
        float* transT  = (float*)(ws + histF);
        char*  tail    = ws + histF + tblF;
        int*   lengths = (int*)tail;
        float* num     = (float*)(tail + 2048);
        float* den     = (float*)(tail + 4096);
        int*   lastp   = (int*)(tail + 6144);

        prep_kernel<<<Tn * Tn / 256, 256, 0, stream>>>(trans, transT);
        crf_fwd2_kernel<<<2 * Bn, 512, 0, stream>>>(logits, start_t, end_t, trans, mask,
                                                    labels, lengths, hist, den, lastp, num);
        bt_loss_kernel<<<Bn + 1, 64, 0, stream>>>(hist, logits, start_t, transT, lastp,
                                                  lengths, num, den, out, out + (size_t)Bn * Sn);
    } else {
        // -------- fallback: proven round-1 path (~17 MB ws) --------
        const size_t histSz = (size_t)Sn * Bn * Tn;
        unsigned char*  hist    = (unsigned char*)ws;
        int*            lengths = (int*)(ws + histSz);
        float*          num     = (float*)(ws + histSz + 512);
        float*          den     = (float*)(ws + histSz + 1024);
        int*            lastp   = (int*)(ws + histSz + 1536);
        __hip_bfloat16* E       = (__hip_bfloat16*)(ws + histSz + 2048);

        compute_E_kernel<<<(Tn * Tn) / 256, 256, 0, stream>>>(trans, E);
        lengths_kernel<<<Bn, 256, 0, stream>>>(mask, lengths);
        fused_fwd_kernel<<<Bn, 1024, 0, stream>>>(logits, start_t, end_t, trans, E,
                                                  lengths, hist, den, lastp);
        numerator_kernel<<<Bn, 256, 0, stream>>>(logits, labels, start_t, end_t, trans,
                                                 lengths, num);
        backtrack_kernel<<<Bn, 64, 0, stream>>>(hist, lastp, lengths, out);
        loss_kernel<<<1, 128, 0, stream>>>(num, den, out + (size_t)Bn * Sn);
    }
}

// Round 4
// 792.678 us; speedup vs baseline: 3.6944x; 1.0048x over previous
//
#include <hip/hip_runtime.h>
#include <hip/hip_bf16.h>
#include <math.h>

#define Bn 128
#define Sn 512
#define Tn 256

typedef float vf32t __attribute__((ext_vector_type(32)));
typedef unsigned int vu16t __attribute__((ext_vector_type(16)));
typedef _Float16 half2_t __attribute__((ext_vector_type(2)));

static __device__ inline float dot2h(unsigned int p, unsigned int e, float acc) {
#if __has_builtin(__builtin_amdgcn_fdot2)
    return __builtin_amdgcn_fdot2(__builtin_bit_cast(half2_t, p),
                                  __builtin_bit_cast(half2_t, e), acc, false);
#else
    half2_t ph = __builtin_bit_cast(half2_t, p), eh = __builtin_bit_cast(half2_t, e);
    return acc + (float)ph.x * (float)eh.x + (float)ph.y * (float)eh.y;
#endif
}

// ===================================================================
// FAST PATH
// ===================================================================

// transT = trans^T (for backtrack); E16 = exp(trans) as f16, packed by row-pairs:
// half index = (i>>1)*512 + c*2 + (i&1)  -> word w = r2*256+c holds rows {2r2, 2r2+1}
__global__ void prep_kernel(const float* __restrict__ trans, float* __restrict__ transT,
                            _Float16* __restrict__ E16) {
    int k = blockIdx.x * blockDim.x + threadIdx.x;   // 65536 threads
    int i = k >> 8, c = k & 255;
    float v = trans[k];
    transT[c * 256 + i] = v;
    E16[((size_t)(i >> 1) * 512) + c * 2 + (i & 1)] = (_Float16)__expf(v);
}

// blocks 0..127: Viterbi fwd (batch b). blocks 128..255: denominator + numerator.
// 512 threads: jp = tid&63 -> 4 cols j0=4jp..4jp+3 ; q = tid>>6 -> rows [32q,32q+32)
__launch_bounds__(512, 2)
__global__ void crf_fwd3_kernel(const float* __restrict__ logits,
                                const float* __restrict__ start_t,
                                const float* __restrict__ end_t,
                                const float* __restrict__ trans,
                                const unsigned int* __restrict__ E16w,
                                const void* __restrict__ mask,
                                const int* __restrict__ labels,
                                int* __restrict__ lengths_out,
                                float* __restrict__ hist,      // [S][B][T] pre-emit best values
                                float* __restrict__ den_out,
                                int* __restrict__ last_out,
                                float* __restrict__ num_out) {
    const int bid = blockIdx.x;
    const bool is_vit = bid < Bn;
    const int b = is_vit ? bid : bid - Bn;
    const int tid = threadIdx.x;
    const int jp = tid & 63;
    const int q  = tid >> 6;          // row-group 0..7
    const int j0 = jp * 4;
    const int i0 = q * 32;
    const int wv = tid >> 6, lane = tid & 63;

    __shared__ __align__(16) float sbuf[Tn];       // state (vit) — f32
    __shared__ __align__(16) _Float16 p16[Tn];     // p (den) — f16
    __shared__ __align__(16) float part[8 * Tn];   // per-(rowgroup,column) partials
    __shared__ float msh[2];
    __shared__ int   lenred[8];
    __shared__ float wredf[8];
    __shared__ int   wredi[8];
    __shared__ float wnum[8];

    // ---- per-block length from mask (dtype auto-detect) ----
    int nz;
    {
        const unsigned int* mu = (const unsigned int*)mask;
        unsigned int w0 = mu[0];
        if (w0 == 1u)                nz = (((const int*)mask)[b * Sn + tid] != 0);
        else if (w0 == 0x3F800000u)  nz = (((const float*)mask)[b * Sn + tid] != 0.0f);
        else                         nz = (((const unsigned char*)mask)[b * Sn + tid] != 0);
    }
    unsigned long long bal = __ballot(nz != 0);
    if (lane == 0) lenred[wv] = __popcll(bal);
    __syncthreads();
    int len = 0;
    #pragma unroll
    for (int w = 0; w < 8; ++w) len += lenred[w];
    if (is_vit && tid == 0) lengths_out[b] = len;

    const float* lg = logits + (size_t)b * Sn * Tn + tid;   // used when tid<256
    const float4* sb4 = (const float4*)sbuf;
    const unsigned int* p16w = (const unsigned int*)p16;

    float cur = 0.0f, emit_cur = 0.0f, emit_next = 0.0f;

    if (is_vit) {
        // ---- register-resident trans columns: 4 cols x 32 rows ----
        vf32t tvA, tvB, tvC, tvD;
        #pragma unroll
        for (int r = 0; r < 32; ++r) {
            float4 v = *(const float4*)(trans + (size_t)(i0 + r) * Tn + j0);
            tvA[r] = v.x; tvB[r] = v.y; tvC[r] = v.z; tvD[r] = v.w;
        }

        if (tid < Tn) {
            cur = start_t[tid] + lg[0];
            sbuf[tid] = cur;
            emit_cur = lg[Tn];
        }
        __syncthreads();

        for (int t = 1; t < len; ++t) {
            if (tid < Tn) {
                int tn = (t + 1 < len) ? (t + 1) : (len - 1);
                emit_next = lg[(size_t)tn * Tn];
            }
            float bA = -INFINITY, bB = -INFINITY, bC = -INFINITY, bD = -INFINITY;
            #pragma unroll
            for (int k = 0; k < 8; ++k) {
                float4 s4 = sb4[q * 8 + k];
                int i = 4 * k;
                float cA0 = s4.x + tvA[i],     cA1 = s4.y + tvA[i + 1];
                float cA2 = s4.z + tvA[i + 2], cA3 = s4.w + tvA[i + 3];
                bA = fmaxf(fmaxf(bA, cA0), cA1); bA = fmaxf(fmaxf(bA, cA2), cA3);
                float cB0 = s4.x + tvB[i],     cB1 = s4.y + tvB[i + 1];
                float cB2 = s4.z + tvB[i + 2], cB3 = s4.w + tvB[i + 3];
                bB = fmaxf(fmaxf(bB, cB0), cB1); bB = fmaxf(fmaxf(bB, cB2), cB3);
                float cC0 = s4.x + tvC[i],     cC1 = s4.y + tvC[i + 1];
                float cC2 = s4.z + tvC[i + 2], cC3 = s4.w + tvC[i + 3];
                bC = fmaxf(fmaxf(bC, cC0), cC1); bC = fmaxf(fmaxf(bC, cC2), cC3);
                float cD0 = s4.x + tvD[i],     cD1 = s4.y + tvD[i + 1];
                float cD2 = s4.z + tvD[i + 2], cD3 = s4.w + tvD[i + 3];
                bD = fmaxf(fmaxf(bD, cD0), cD1); bD = fmaxf(fmaxf(bD, cD2), cD3);
            }
            *(float4*)(part + q * Tn + j0) = make_float4(bA, bB, bC, bD);
            __syncthreads();
            if (tid < Tn) {
                float bb = part[tid];
                #pragma unroll
                for (int q2 = 1; q2 < 8; ++q2) bb = fmaxf(bb, part[q2 * Tn + tid]);
                hist[((size_t)t * Bn + b) * Tn + tid] = bb;
                cur = bb + emit_cur;
                emit_cur = emit_next;
                sbuf[tid] = cur;
            }
            __syncthreads();
        }

        // epilogue: last = argmax_j(cur + end_t[j]), ties -> smallest j
        float bv = -INFINITY; int bj = 0;
        if (tid < Tn) { bv = cur + end_t[tid]; bj = tid; }
        #pragma unroll
        for (int off = 32; off; off >>= 1) {
            float ov = __shfl_xor(bv, off);
            int   oj = __shfl_xor(bj, off);
            if (ov > bv || (ov == bv && oj < bj)) { bv = ov; bj = oj; }
        }
        if (lane == 0) { wredf[wv] = bv; wredi[wv] = bj; }
        __syncthreads();
        if (tid == 0) {
            float BB = wredf[0]; int AA = wredi[0];
            #pragma unroll
            for (int w = 1; w < 4; ++w)
                if (wredf[w] > BB || (wredf[w] == BB && wredi[w] < AA)) { BB = wredf[w]; AA = wredi[w]; }
            last_out[b] = AA;
        }
    } else {
        // ---- register-resident exp(trans) as packed f16 row-pairs: 4 cols x 16 pairs ----
        vu16t tdA, tdB, tdC, tdD;
        #pragma unroll
        for (int k = 0; k < 16; ++k) {
            uint4 v = *(const uint4*)(E16w + (size_t)(16 * q + k) * Tn + j0);
            tdA[k] = v.x; tdB[k] = v.y; tdC[k] = v.z; tdD[k] = v.w;
        }

        const float SHIFT = 9.0f;
        float pbase = 0.0f;
        if (tid < Tn) {
            cur = start_t[tid] + lg[0];
            if (tid == 0) msh[0] = cur;
            emit_cur = lg[Tn];
        }
        __syncthreads();
        if (tid < Tn) {
            pbase = msh[0] + SHIFT;
            p16[tid] = (_Float16)__expf(cur - pbase);
        }
        __syncthreads();

        for (int t = 1; t < len; ++t) {
            if (tid < Tn) {
                int tn = (t + 1 < len) ? (t + 1) : (len - 1);
                emit_next = lg[(size_t)tn * Tn];
            }
            // phase 1: partial dot(p16, E16) over my 32 rows for my 4 cols
            float sA = 0.f, sB = 0.f, sC = 0.f, sD = 0.f;
            #pragma unroll
            for (int k = 0; k < 8; ++k) {
                uint2 pp = *(const uint2*)(p16w + q * 16 + 2 * k);
                int i = 2 * k;
                sA = dot2h(pp.x, tdA[i], sA); sA = dot2h(pp.y, tdA[i + 1], sA);
                sB = dot2h(pp.x, tdB[i], sB); sB = dot2h(pp.y, tdB[i + 1], sB);
                sC = dot2h(pp.x, tdC[i], sC); sC = dot2h(pp.y, tdC[i + 1], sC);
                sD = dot2h(pp.x, tdD[i], sD); sD = dot2h(pp.y, tdD[i + 1], sD);
            }
            *(float4*)(part + q * Tn + j0) = make_float4(sA, sB, sC, sD);
            __syncthreads();
            // phase 2: combine, log, re-exponentiate with lag-1 shifted base
            if (tid < Tn) {
                float tot = part[tid];
                #pragma unroll
                for (int q2 = 1; q2 < 8; ++q2) tot += part[q2 * Tn + tid];
                float nb = msh[(t - 1) & 1];           // cur_0 from step t-1
                cur = pbase + __logf(tot) + emit_cur;
                emit_cur = emit_next;
                p16[tid] = (_Float16)__expf(cur - nb - SHIFT);
                pbase = nb + SHIFT;
                if (tid == 0) msh[t & 1] = cur;
            }
            __syncthreads();
        }

        // epilogue: den = logsumexp_j(cur + end_t[j]) (exact fp32)
        float v2 = (tid < Tn) ? (cur + end_t[tid]) : -INFINITY;
        float wm = v2;
        #pragma unroll
        for (int off = 32; off; off >>= 1) wm = fmaxf(wm, __shfl_xor(wm, off));
        if (lane == 0) wredf[wv] = wm;
        __syncthreads();
        float M = fmaxf(fmaxf(wredf[0], wredf[1]), fmaxf(wredf[2], wredf[3]));
        float ex = (tid < Tn) ? __expf(v2 - M) : 0.0f;
        #pragma unroll
        for (int off = 32; off; off >>= 1) ex += __shfl_xor(ex, off);
        if (lane == 0) wnum[wv] = ex;
        __syncthreads();
        if (tid == 0) den_out[b] = M + __logf(wnum[0] + wnum[1] + wnum[2] + wnum[3]);
        __syncthreads();

        // ---- numerator (fused; vit blocks are the wall) ----
        float acc = 0.0f;
        if (tid >= 1 && tid < len) {
            int prev = labels[b * Sn + tid - 1], curl = labels[b * Sn + tid];
            acc = trans[prev * Tn + curl] + logits[((size_t)b * Sn + tid) * Tn + curl];
        }
        #pragma unroll
        for (int off = 32; off; off >>= 1) acc += __shfl_xor(acc, off);
        if (lane == 0) wnum[wv] = acc;
        __syncthreads();
        if (tid == 0) {
            float s = 0.0f;
            #pragma unroll
            for (int w = 0; w < 8; ++w) s += wnum[w];
            int l0 = labels[b * Sn];
            int ll = labels[b * Sn + len - 1];
            num_out[b] = start_t[l0] + logits[(size_t)b * Sn * Tn + l0] + s + end_t[ll];
        }
    }
}

// ---------------- equality backtrack (blocks 0..127) + loss (block 128) ----------------
__global__ void bt_loss_kernel(const float* __restrict__ hist,
                               const float* __restrict__ logits,
                               const float* __restrict__ start_t,
                               const float* __restrict__ transT,
                               const int* __restrict__ last,
                               const int* __restrict__ lengths,
                               const float* __restrict__ num,
                               const float* __restrict__ den,
                               float* __restrict__ pred,
                               float* __restrict__ out_loss) {
    const int lane = threadIdx.x;   // 64 threads
    if (blockIdx.x == Bn) {
        float v = (den[lane] - num[lane]) + (den[lane + 64] - num[lane + 64]);
        #pragma unroll
        for (int off = 32; off; off >>= 1) v += __shfl_xor(v, off);
        if (lane == 0) out_loss[0] = v * (1.0f / 128.0f);
        return;
    }
    const int b = blockIdx.x;
    const int len = lengths[b], len1 = len - 1;
    __shared__ int tg[Sn];
    int tag = last[b];
    if (lane == 0) tg[len1] = tag;
    float target = hist[((size_t)len1 * Bn + b) * Tn + tag];

    const float4* lgrow = (const float4*)(logits + (size_t)b * Sn * Tn) + lane;
    const char* histb = (const char*)(hist + (size_t)b * Tn);
    float4 s4 = *((const float4*)start_t + lane);

    const int PF = 8;
    float4 hbuf[PF], ebuf[PF];
    #pragma unroll
    for (int qq = 0; qq < PF; ++qq) {
        int r = len1 - 1 - qq;
        if (r >= 0) {
            int rh = (r > 1) ? r : 1;
            ebuf[qq] = lgrow[(size_t)r * 64];
            hbuf[qq] = *((const float4*)(histb + (size_t)rh * (Bn * Tn * 4)) + lane);
        }
    }

    for (int k = 0; k < len1; ++k) {
        int r = len1 - 1 - k;               // previous-time row index
        // serial-critical load FIRST so later prefetches don't gate its waitcnt
        float4 t4 = *((const float4*)(transT + (size_t)tag * Tn) + lane);
        float4 h4 = hbuf[k & (PF - 1)], e4 = ebuf[k & (PF - 1)];
        int rp = r - PF;                    // prefetch PF steps ahead (issued AFTER t4)
        if (rp >= 0) {
            int rh = (rp > 1) ? rp : 1;
            ebuf[k & (PF - 1)] = lgrow[(size_t)rp * 64];
            hbuf[k & (PF - 1)] = *((const float4*)(histb + (size_t)rh * (Bn * Tn * 4)) + lane);
        }
        float4 sv;
        if (r > 0) {
            sv.x = h4.x + e4.x; sv.y = h4.y + e4.y; sv.z = h4.z + e4.z; sv.w = h4.w + e4.w;
        } else {
            sv.x = s4.x + e4.x; sv.y = s4.y + e4.y; sv.z = s4.z + e4.z; sv.w = s4.w + e4.w;
        }
        int m4 = ((sv.x + t4.x) == target ? 1 : 0)
               | ((sv.y + t4.y) == target ? 2 : 0)
               | ((sv.z + t4.z) == target ? 4 : 0)
               | ((sv.w + t4.w) == target ? 8 : 0);
        unsigned long long bb = __ballot(m4 != 0);
        int L = __ffsll(bb) - 1;
        int mm = __shfl(m4, L);
        int slot = __ffs(mm) - 1;
        tag = L * 4 + slot;
        if (lane == 0) tg[r] = tag;
        float hv = (slot == 0) ? h4.x : (slot == 1) ? h4.y : (slot == 2) ? h4.z : h4.w;
        target = __shfl(hv, L);              // hist[r][tag], valid when r > 0
    }
    __syncthreads();
    for (int t = lane; t < Sn; t += 64)
        pred[(size_t)b * Sn + t] = (t < len) ? (float)tg[t] : 0.0f;
}

// ===================================================================
// FALLBACK PATH (round-1, proven): used only if ws_size is too small
// ===================================================================

__global__ void compute_E_kernel(const float* __restrict__ trans, __hip_bfloat16* __restrict__ E) {
    int k = blockIdx.x * blockDim.x + threadIdx.x;
    if (k < Tn * Tn) E[k] = __float2bfloat16(__expf(trans[k]));
}

__global__ void lengths_kernel(const void* __restrict__ mask, int* __restrict__ lengths) {
    int b = blockIdx.x, tid = threadIdx.x;
    const unsigned int* mu = (const unsigned int*)mask;
    unsigned int w0 = mu[0];
    int cnt = 0;
    if (w0 == 1u) {
        const int* mi = (const int*)mask;
        for (int t = tid; t < Sn; t += 256) cnt += (mi[b * Sn + t] != 0);
    } else if (w0 == 0x3F800000u) {
        const float* mf = (const float*)mask;
        for (int t = tid; t < Sn; t += 256) cnt += (mf[b * Sn + t] != 0.0f);
    } else {
        const unsigned char* mb = (const unsigned char*)mask;
        for (int t = tid; t < Sn; t += 256) cnt += (mb[b * Sn + t] != 0);
    }
    for (int off = 32; off; off >>= 1) cnt += __shfl_xor(cnt, off);
    __shared__ int red[4];
    if ((tid & 63) == 0) red[tid >> 6] = cnt;
    __syncthreads();
    if (tid == 0) lengths[b] = red[0] + red[1] + red[2] + red[3];
}

__global__ void numerator_kernel(const float* __restrict__ logits, const int* __restrict__ labels,
                                 const float* __restrict__ start_t, const float* __restrict__ end_t,
                                 const float* __restrict__ trans, const int* __restrict__ lengths,
                                 float* __restrict__ num) {
    int b = blockIdx.x, tid = threadIdx.x;
    int len = lengths[b];
    float acc = 0.0f;
    for (int t = tid + 1; t < len; t += 256) {
        int prev = labels[b * Sn + t - 1], cur = labels[b * Sn + t];
        acc += trans[prev * Tn + cur] + logits[((size_t)b * Sn + t) * Tn + cur];
    }
    for (int off = 32; off; off >>= 1) acc += __shfl_xor(acc, off);
    __shared__ float red[4];
    if ((tid & 63) == 0) red[tid >> 6] = acc;
    __syncthreads();
    if (tid == 0) {
        int l0 = labels[b * Sn];
        int ll = labels[b * Sn + len - 1];
        num[b] = start_t[l0] + logits[(size_t)b * Sn * Tn + l0]
               + red[0] + red[1] + red[2] + red[3] + end_t[ll];
    }
}

__launch_bounds__(1024)
__global__ void fused_fwd_kernel(const float* __restrict__ logits,
                                 const float* __restrict__ start_t,
                                 const float* __restrict__ end_t,
                                 const float* __restrict__ trans,
                                 const __hip_bfloat16* __restrict__ E,
                                 const int* __restrict__ lengths,
                                 unsigned char* __restrict__ hist,
                                 float* __restrict__ den_out,
                                 int* __restrict__ last_out) {
    int b = blockIdx.x;
    int tid = threadIdx.x;
    int j = tid & 255;
    int h = tid >> 8;
    int i0 = h * 64;

    __shared__ __align__(16) float sden[Tn];
    __shared__ __align__(16) float svit[Tn];
    __shared__ __align__(16) float p[Tn];
    __shared__ float redf[16];
    __shared__ float reds[16];
    __shared__ float redb[16];
    __shared__ int   redbi[16];
    __shared__ float pd[1024];
    __shared__ float pv[1024];
    __shared__ int   pa[1024];

    int len = lengths[b];
    if (tid < Tn) {
        float v = start_t[j] + logits[(size_t)b * Sn * Tn + j];
        sden[j] = v;
        svit[j] = v;
    }
    __syncthreads();

    for (int t = 1; t < len; ++t) {
        float v = sden[j];
        for (int off = 32; off; off >>= 1) v = fmaxf(v, __shfl_xor(v, off));
        if ((tid & 63) == 0) redf[tid >> 6] = v;
        __syncthreads();
        float m = redf[0];
        #pragma unroll
        for (int w = 1; w < 16; ++w) m = fmaxf(m, redf[w]);
        if (tid < Tn) p[j] = __expf(sden[j] - m);
        __syncthreads();

        float s = 0.0f, best = -INFINITY;
        int arg = 0;
        const float* tr = trans + (size_t)i0 * Tn + j;
        const __hip_bfloat16* er = E + (size_t)i0 * Tn + j;
        #pragma unroll 4
        for (int i = i0; i < i0 + 64; i += 4) {
            float4 p4  = *(const float4*)(p + i);
            float4 sv4 = *(const float4*)(svit + i);
            float tr0 = tr[0 * Tn], tr1 = tr[1 * Tn], tr2 = tr[2 * Tn], tr3 = tr[3 * Tn];
            float e0 = __bfloat162float(er[0 * Tn]);
            float e1 = __bfloat162float(er[1 * Tn]);
            float e2 = __bfloat162float(er[2 * Tn]);
            float e3 = __bfloat162float(er[3 * Tn]);
            tr += 4 * Tn; er += 4 * Tn;
            s = fmaf(p4.x, e0, s); s = fmaf(p4.y, e1, s);
            s = fmaf(p4.z, e2, s); s = fmaf(p4.w, e3, s);
            float c0 = sv4.x + tr0; if (c0 > best) { best = c0; arg = i + 0; }
            float c1 = sv4.y + tr1; if (c1 > best) { best = c1; arg = i + 1; }
            float c2 = sv4.z + tr2; if (c2 > best) { best = c2; arg = i + 2; }
            float c3 = sv4.w + tr3; if (c3 > best) { best = c3; arg = i + 3; }
        }
        pd[tid] = s; pv[tid] = best; pa[tid] = arg;
        __syncthreads();

        if (tid < Tn) {
            float ss = pd[j] + pd[j + 256] + pd[j + 512] + pd[j + 768];
            float bb = pv[j]; int aa = pa[j];
            if (pv[j + 256] > bb) { bb = pv[j + 256]; aa = pa[j + 256]; }
            if (pv[j + 512] > bb) { bb = pv[j + 512]; aa = pa[j + 512]; }
            if (pv[j + 768] > bb) { bb = pv[j + 768]; aa = pa[j + 768]; }
            float emit = logits[((size_t)b * Sn + t) * Tn + j];
            sden[j] = m + __logf(ss) + emit;
            svit[j] = bb + emit;
            hist[((size_t)t * Bn + b) * Tn + j] = (unsigned char)aa;
        }
        __syncthreads();
    }

    float v2d = sden[j] + end_t[j];
    float M = v2d;
    for (int off = 32; off; off >>= 1) M = fmaxf(M, __shfl_xor(M, off));
    if ((tid & 63) == 0) redf[tid >> 6] = M;
    __syncthreads();
    M = redf[0];
    #pragma unroll
    for (int w = 1; w < 16; ++w) M = fmaxf(M, redf[w]);

    float ex = (tid < Tn) ? __expf(v2d - M) : 0.0f;
    for (int off = 32; off; off >>= 1) ex += __shfl_xor(ex, off);

    float v2v = svit[j] + end_t[j];
    float bv = v2v; int bj = j;
    for (int off = 32; off; off >>= 1) {
        float ov = __shfl_xor(bv, off); int oj = __shfl_xor(bj, off);
        if (ov > bv || (ov == bv && oj < bj)) { bv = ov; bj = oj; }
    }
    if ((tid & 63) == 0) { reds[tid >> 6] = ex; redb[tid >> 6] = bv; redbi[tid >> 6] = bj; }
    __syncthreads();
    if (tid == 0) {
        float sum = 0.0f;
        #pragma unroll
        for (int w = 0; w < 16; ++w) sum += reds[w];
        den_out[b] = M + __logf(sum);
        float BB = redb[0]; int AA = redbi[0];
        #pragma unroll
        for (int w = 1; w < 16; ++w)
            if (redb[w] > BB || (redb[w] == BB && redbi[w] < AA)) { BB = redb[w]; AA = redbi[w]; }
        last_out[b] = AA;
    }
}

__global__ void backtrack_kernel(const unsigned char* __restrict__ hist,
                                 const int* __restrict__ last,
                                 const int* __restrict__ lengths,
                                 float* __restrict__ pred) {
    int b = blockIdx.x, lane = threadIdx.x;
    int len = lengths[b];
    int len1 = len - 1;
    __shared__ int tg[Sn];
    int tag = last[b];

    const int P = 16;
    unsigned int buf[P];
    #pragma unroll
    for (int qq = 0; qq < P; ++qq) {
        int r = len1 - qq;
        if (qq < len1)
            buf[qq] = *(const unsigned int*)(hist + ((size_t)r * Bn + b) * Tn + lane * 4);
    }
    if (lane == 0) tg[len1] = tag;
    for (int qq = 0; qq < len1; ++qq) {
        unsigned int w = buf[qq & (P - 1)];
        int sel = __shfl((int)w, tag >> 2, 64);
        tag = (sel >> ((tag & 3) * 8)) & 255;
        int t = len1 - 1 - qq;
        if (lane == 0) tg[t] = tag;
        int rn = len1 - qq - P;
        if (rn >= 1)
            buf[qq & (P - 1)] = *(const unsigned int*)(hist + ((size_t)rn * Bn + b) * Tn + lane * 4);
    }
    __syncthreads();
    for (int t = lane; t < Sn; t += 64)
        pred[(size_t)b * Sn + t] = (t < len) ? (float)tg[t] : 0.0f;
}

__global__ void loss_kernel(const float* __restrict__ num, const float* __restrict__ den,
                            float* __restrict__ out_loss) {
    int tid = threadIdx.x;
    float v = den[tid] - num[tid];
    for (int off = 32; off; off >>= 1) v += __shfl_xor(v, off);
    __shared__ float r2[2];
    if ((tid & 63) == 0) r2[tid >> 6] = v;
    __syncthreads();
    if (tid == 0) out_loss[0] = (r2[0] + r2[1]) * (1.0f / 128.0f);
}

// ===================================================================

extern "C" void kernel_launch(void* const* d_in, const int* in_sizes, int n_in,
                              void* d_out, int out_size, void* d_ws, size_t ws_size,
                              hipStream_t stream) {
    const float* logits  = (const float*)d_in[0];
    const void*  mask    = d_in[1];
    const int*   labels  = (const int*)d_in[2];
    const float* start_t = (const float*)d_in[3];
    const float* end_t   = (const float*)d_in[4];
    const float* trans   = (const float*)d_in[5];
    float* out = (float*)d_out;   // [B*S] pred as float, then [1] loss

    char* ws = (char*)d_ws;
    const size_t histF = (size_t)Sn * Bn * Tn * 4;           // 67.1 MB fp32 best-value hist
    const size_t tblF  = (size_t)Tn * Tn * 4;                // 256 KB
    const size_t e16F  = (size_t)Tn * Tn * 2;                // 128 KB
    const size_t needF = histF + tblF + e16F + 8192;

    if (ws_size >= needF) {
        // -------- fast path --------
        float*        hist    = (float*)ws;
        float*        transT  = (float*)(ws + histF);
        _Float16*     E16     = (_Float16*)(ws + histF + tblF);
        char*         tail    = ws + histF + tblF + e16F;
        int*          lengths = (int*)tail;
        float*        num     = (float*)(tail + 2048);
        float*        den     = (float*)(tail + 4096);
        int*          lastp   = (int*)(tail + 6144);

        prep_kernel<<<Tn * Tn / 256, 256, 0, stream>>>(trans, transT, E16);
        crf_fwd3_kernel<<<2 * Bn, 512, 0, stream>>>(logits, start_t, end_t, trans,
                                                    (const unsigned int*)E16, mask,
                                                    labels, lengths, hist, den, lastp, num);
        bt_loss_kernel<<<Bn + 1, 64, 0, stream>>>(hist, logits, start_t, transT, lastp,
                                                  lengths, num, den, out, out + (size_t)Bn * Sn);
    } else {
        // -------- fallback: proven round-1 path (~17 MB ws) --------
        const size_t histSz = (size_t)Sn * Bn * Tn;
        unsigned char*  hist    = (unsigned char*)ws;
        int*            lengths = (int*)(ws + histSz);
        float*          num     = (float*)(ws + histSz + 512);
        float*          den     = (float*)(ws + histSz + 1024);
        int*            lastp   = (int*)(ws + histSz + 1536);
        __hip_bfloat16* E       = (__hip_bfloat16*)(ws + histSz + 2048);

        compute_E_kernel<<<(Tn * Tn) / 256, 256, 0, stream>>>(trans, E);
        lengths_kernel<<<Bn, 256, 0, stream>>>(mask, lengths);
        fused_fwd_kernel<<<Bn, 1024, 0, stream>>>(logits, start_t, end_t, trans, E,
                                                  lengths, hist, den, lastp);
        numerator_kernel<<<Bn, 256, 0, stream>>>(logits, labels, start_t, end_t, trans,
                                                 lengths, num);
        backtrack_kernel<<<Bn, 64, 0, stream>>>(hist, lastp, lengths, out);
        loss_kernel<<<1, 128, 0, stream>>>(num, den, out + (size_t)Bn * Sn);
    }
}